// Round 2
// baseline (36469.354 us; speedup 1.0000x reference)
//
#include <hip/hip_runtime.h>
#include <math.h>

// ---------------------------------------------------------------------------
// PhyRNN: 2-layer LSTM (B=64, T=3000, I=8, H=128) + FC head + double FD deriv.
//
// R2 changes vs R1 (which ran at 16.6 ms, VALUBusy 6%):
//  * VGPR_Count was 128 -> the per-thread float w[128] weight row could not be
//    register-resident (spill/remat => every FMA pulled its weight from
//    memory). Fix: amdgpu_waves_per_eu(2,2) pins 2 waves/EU => 256-VGPR
//    budget. Only 64 blocks exist (1/CU), so extra occupancy is worthless.
//  * Thread remap tid = j*4 + gt: the 4 gates of unit j live in adjacent
//    lanes; gate combine via 3 __shfl_xor => ONE barrier/step (was 2) and no
//    part_f/g/o LDS round trip. h_s double-buffered.
//  * 4-way accumulator split in the K-loop (break dependent-FMA chain).
//  * layer1: xp chunk results parked in LDS so phase-B t-loop stays rolled
//    (keeps the hot loop ~1.4 KB of I$); W_ih/W_hh rows reloaded per chunk
//    from L2 (64 loads/thread/chunk, amortized 2.7 insts/step).
//
// Precision: fp32 throughout (no fp32 MFMA on CDNA4; bf16 noise would be
// amplified ~1e3-1e4x by the double time-derivative).
// ws: h buffer 98.304 MB + y 0.768 MB + z 0.768 MB (proven to fit in R1).
// ---------------------------------------------------------------------------

#define T_STEPS 3000
#define BATCH   64
#define HID     128
#define GATES   512
#define CHUNK   24      // 3000 = 125 * 24; xp LDS = 24*512*4 = 48 KB
#define INV_DT  50.0f   // 1/0.02

__device__ __forceinline__ float sigmoid_(float x) {
    return 1.0f / (1.0f + __expf(-x));
}
__device__ __forceinline__ float tanh_(float x) {
    return 1.0f - 2.0f / (__expf(2.0f * x) + 1.0f);
}

// ---------------------------------------------------------------- layer 0 ---
// 64 blocks (1/batch), 512 threads. tid = j*4 + gt; weight row r = gt*128+j.
__global__ __launch_bounds__(512)
__attribute__((amdgpu_waves_per_eu(2, 2)))
void lstm_layer0(const float* __restrict__ x,      // [64][3000][8]
                 const float* __restrict__ w_ih,   // [512][8]
                 const float* __restrict__ w_hh,   // [512][128]
                 const float* __restrict__ b_ih,
                 const float* __restrict__ b_hh,
                 float* __restrict__ h_out)        // [64][3000][128]
{
    const int b   = blockIdx.x;
    const int tid = threadIdx.x;
    const int j   = tid >> 2;           // hidden unit 0..127
    const int gt  = tid & 3;            // gate type: 0=i 1=f 2=g 3=o
    const int r   = gt * HID + j;       // row in the [512 x *] weight matrix

    __shared__ __align__(16) float h_s[2][HID];

    float w[HID];                       // W_hh row, register-resident
#pragma unroll
    for (int i = 0; i < HID; i += 4) {
        float4 v = *(const float4*)(w_hh + (size_t)r * HID + i);
        w[i] = v.x; w[i+1] = v.y; w[i+2] = v.z; w[i+3] = v.w;
    }
    float wi[8];
#pragma unroll
    for (int i = 0; i < 8; i += 4) {
        float4 v = *(const float4*)(w_ih + (size_t)r * 8 + i);
        wi[i] = v.x; wi[i+1] = v.y; wi[i+2] = v.z; wi[i+3] = v.w;
    }
    const float bias = b_ih[r] + b_hh[r];
    float c = 0.0f;                     // valid in gt==0 threads

    if (tid < HID) h_s[0][tid] = 0.0f;  // h[-1] = 0 (read buffer at t=0)
    __syncthreads();

    const float* xrow = x + (size_t)b * T_STEPS * 8;
    float* hb = h_out + (size_t)b * T_STEPS * HID;

    for (int t = 0; t < T_STEPS; ++t) {
        const int rb = t & 1;
        float4 xa = *(const float4*)(xrow + t * 8);
        float4 xc = *(const float4*)(xrow + t * 8 + 4);
        float acc0 = bias
                   + wi[0]*xa.x + wi[1]*xa.y + wi[2]*xa.z + wi[3]*xa.w
                   + wi[4]*xc.x + wi[5]*xc.y + wi[6]*xc.z + wi[7]*xc.w;
        float acc1 = 0.0f, acc2 = 0.0f, acc3 = 0.0f;
#pragma unroll
        for (int k4 = 0; k4 < HID / 4; k4 += 4) {
            float4 h0 = *(const float4*)(&h_s[rb][4*k4]);
            float4 h1 = *(const float4*)(&h_s[rb][4*k4 + 4]);
            float4 h2 = *(const float4*)(&h_s[rb][4*k4 + 8]);
            float4 h3 = *(const float4*)(&h_s[rb][4*k4 + 12]);
            acc0 += w[4*k4   ]*h0.x + w[4*k4+ 1]*h0.y + w[4*k4+ 2]*h0.z + w[4*k4+ 3]*h0.w;
            acc1 += w[4*k4+ 4]*h1.x + w[4*k4+ 5]*h1.y + w[4*k4+ 6]*h1.z + w[4*k4+ 7]*h1.w;
            acc2 += w[4*k4+ 8]*h2.x + w[4*k4+ 9]*h2.y + w[4*k4+10]*h2.z + w[4*k4+11]*h2.w;
            acc3 += w[4*k4+12]*h3.x + w[4*k4+13]*h3.y + w[4*k4+14]*h3.z + w[4*k4+15]*h3.w;
        }
        float accs = (acc0 + acc1) + (acc2 + acc3);

        // per-lane activation, then gather the 4 gates of unit j (lanes 4j..4j+3)
        float av = (gt == 2) ? tanh_(accs) : sigmoid_(accs);
        float t1 = __shfl_xor(av, 1);
        float t2 = __shfl_xor(av, 2);
        float t3 = __shfl_xor(t1, 2);
        if (gt == 0) {                  // av=sig(i) t1=sig(f) t2=tanh(g) t3=sig(o)
            c = t1 * c + av * t2;
            float h = t3 * tanh_(c);
            h_s[rb ^ 1][j] = h;
            hb[(size_t)t * HID + j] = h;
        }
        __syncthreads();
    }
}

// ---------------------------------------------------------------- layer 1 ---
// Same layout. Per CHUNK: phase A computes xp[tau][tid] = bias + W_ih . h1
// (parallel, weights resident, uniform global loads of h1), then phase B runs
// the serial recurrence. h2 overwrites h1 in place (barrier between phases).
__global__ __launch_bounds__(512)
__attribute__((amdgpu_waves_per_eu(2, 2)))
void lstm_layer1(const float* __restrict__ w_ih,   // [512][128]
                 const float* __restrict__ w_hh,   // [512][128]
                 const float* __restrict__ b_ih,
                 const float* __restrict__ b_hh,
                 float* __restrict__ h_buf)        // in: h1, out: h2 (in place)
{
    const int b   = blockIdx.x;
    const int tid = threadIdx.x;
    const int j   = tid >> 2;
    const int gt  = tid & 3;
    const int r   = gt * HID + j;

    __shared__ __align__(16) float xp_s[CHUNK][GATES];   // 48 KB
    __shared__ __align__(16) float h_s[2][HID];

    const float bias = b_ih[r] + b_hh[r];
    float c = 0.0f;
    if (tid < HID) h_s[0][tid] = 0.0f;
    __syncthreads();

    float* hbB = h_buf + (size_t)b * T_STEPS * HID;
    float w[HID];

    for (int t0 = 0; t0 < T_STEPS; t0 += CHUNK) {
        // ---- load W_ih row (L2-resident, 32 float4)
#pragma unroll
        for (int i = 0; i < HID; i += 4) {
            float4 v = *(const float4*)(w_ih + (size_t)r * HID + i);
            w[i] = v.x; w[i+1] = v.y; w[i+2] = v.z; w[i+3] = v.w;
        }
        // ---- phase A: xp_s[tau][tid] = bias + W_ih[r] . h1[t0+tau]
        const float* hp = hbB + (size_t)t0 * HID;
#pragma unroll 2
        for (int tau = 0; tau < CHUNK; ++tau) {
            float a0 = bias, a1 = 0.0f, a2 = 0.0f, a3 = 0.0f;
#pragma unroll
            for (int k4 = 0; k4 < HID / 4; k4 += 4) {
                float4 h0 = *(const float4*)(hp + tau*HID + 4*k4);
                float4 h1 = *(const float4*)(hp + tau*HID + 4*k4 + 4);
                float4 h2 = *(const float4*)(hp + tau*HID + 4*k4 + 8);
                float4 h3 = *(const float4*)(hp + tau*HID + 4*k4 + 12);
                a0 += w[4*k4   ]*h0.x + w[4*k4+ 1]*h0.y + w[4*k4+ 2]*h0.z + w[4*k4+ 3]*h0.w;
                a1 += w[4*k4+ 4]*h1.x + w[4*k4+ 5]*h1.y + w[4*k4+ 6]*h1.z + w[4*k4+ 7]*h1.w;
                a2 += w[4*k4+ 8]*h2.x + w[4*k4+ 9]*h2.y + w[4*k4+10]*h2.z + w[4*k4+11]*h2.w;
                a3 += w[4*k4+12]*h3.x + w[4*k4+13]*h3.y + w[4*k4+14]*h3.z + w[4*k4+15]*h3.w;
            }
            xp_s[tau][tid] = (a0 + a1) + (a2 + a3);
        }
        // ---- swap to W_hh row
#pragma unroll
        for (int i = 0; i < HID; i += 4) {
            float4 v = *(const float4*)(w_hh + (size_t)r * HID + i);
            w[i] = v.x; w[i+1] = v.y; w[i+2] = v.z; w[i+3] = v.w;
        }
        __syncthreads();   // all h1 reads done before h2 writes; xp_s visible

        // ---- phase B: serial recurrence over the chunk
#pragma unroll 1
        for (int tt = 0; tt < CHUNK; ++tt) {
            const int t  = t0 + tt;
            const int rb = t & 1;
            float acc0 = xp_s[tt][tid];
            float acc1 = 0.0f, acc2 = 0.0f, acc3 = 0.0f;
#pragma unroll
            for (int k4 = 0; k4 < HID / 4; k4 += 4) {
                float4 h0 = *(const float4*)(&h_s[rb][4*k4]);
                float4 h1 = *(const float4*)(&h_s[rb][4*k4 + 4]);
                float4 h2 = *(const float4*)(&h_s[rb][4*k4 + 8]);
                float4 h3 = *(const float4*)(&h_s[rb][4*k4 + 12]);
                acc0 += w[4*k4   ]*h0.x + w[4*k4+ 1]*h0.y + w[4*k4+ 2]*h0.z + w[4*k4+ 3]*h0.w;
                acc1 += w[4*k4+ 4]*h1.x + w[4*k4+ 5]*h1.y + w[4*k4+ 6]*h1.z + w[4*k4+ 7]*h1.w;
                acc2 += w[4*k4+ 8]*h2.x + w[4*k4+ 9]*h2.y + w[4*k4+10]*h2.z + w[4*k4+11]*h2.w;
                acc3 += w[4*k4+12]*h3.x + w[4*k4+13]*h3.y + w[4*k4+14]*h3.z + w[4*k4+15]*h3.w;
            }
            float accs = (acc0 + acc1) + (acc2 + acc3);

            float av = (gt == 2) ? tanh_(accs) : sigmoid_(accs);
            float t1 = __shfl_xor(av, 1);
            float t2 = __shfl_xor(av, 2);
            float t3 = __shfl_xor(t1, 2);
            if (gt == 0) {
                c = t1 * c + av * t2;
                float h = t3 * tanh_(c);
                h_s[rb ^ 1][j] = h;
                hbB[(size_t)t * HID + j] = h;    // h2 overwrites h1
            }
            __syncthreads();
        }
    }
}

// ---------------------------------------------------------------- FC head ---
__global__ void fc_head(const float* __restrict__ h_buf,  // h2 [64][3000][128]
                        const float* __restrict__ fc1_w, const float* __restrict__ fc1_b,
                        const float* __restrict__ fc2_w, const float* __restrict__ fc2_b,
                        const float* __restrict__ fc3_w, const float* __restrict__ fc3_b,
                        float* __restrict__ y_t)          // [3000][64]
{
    int idx = blockIdx.x * blockDim.x + threadIdx.x;   // idx = t*64 + b
    if (idx >= T_STEPS * BATCH) return;
    int t = idx >> 6, b = idx & 63;

    const float* h = h_buf + (size_t)b * T_STEPS * HID + (size_t)t * HID;
    float hv[HID];
#pragma unroll
    for (int k = 0; k < HID; k += 4) {
        float4 v = *(const float4*)(h + k);
        hv[k] = v.x; hv[k+1] = v.y; hv[k+2] = v.z; hv[k+3] = v.w;
    }
    float y1[16];
#pragma unroll
    for (int jo = 0; jo < 16; ++jo) {
        float a = fc1_b[jo];
#pragma unroll
        for (int k = 0; k < HID; k += 4) {
            float4 wv = *(const float4*)(fc1_w + jo * HID + k);
            a += wv.x*hv[k] + wv.y*hv[k+1] + wv.z*hv[k+2] + wv.w*hv[k+3];
        }
        y1[jo] = fmaxf(a, 0.0f);
    }
    float y2[4];
#pragma unroll
    for (int jo = 0; jo < 4; ++jo) {
        float a = fc2_b[jo];
#pragma unroll
        for (int k = 0; k < 16; ++k) a += fc2_w[jo * 16 + k] * y1[k];
        y2[jo] = fmaxf(a, 0.0f);
    }
    float y = fc3_b[0];
#pragma unroll
    for (int k = 0; k < 4; ++k) y += fc3_w[k] * y2[k];

    y_t[idx] = y;   // coalesced: idx = t*64+b
}

// ------------------------------------------------------------- FD stencil ---
__global__ void deriv_k(const float* __restrict__ in,   // [3000][64]
                        float* __restrict__ outp,
                        int transpose_out)
{
    int idx = blockIdx.x * blockDim.x + threadIdx.x;
    if (idx >= T_STEPS * BATCH) return;
    int t = idx >> 6, b = idx & 63;
    float v;
    if (t == 0) {
        v = (-1.5f * in[b] + 2.0f * in[64 + b] - 0.5f * in[128 + b]) * INV_DT;
    } else if (t == T_STEPS - 1) {
        v = (0.5f * in[(t-2)*64 + b] - 2.0f * in[(t-1)*64 + b] + 1.5f * in[t*64 + b]) * INV_DT;
    } else {
        v = (in[(t+1)*64 + b] - in[(t-1)*64 + b]) * (0.5f * INV_DT);
    }
    if (transpose_out) outp[(size_t)b * T_STEPS + t] = v;   // final out[b][t]
    else               outp[idx] = v;
}

// ------------------------------------------------------------------ launch --
extern "C" void kernel_launch(void* const* d_in, const int* in_sizes, int n_in,
                              void* d_out, int out_size, void* d_ws, size_t ws_size,
                              hipStream_t stream)
{
    const float* x     = (const float*)d_in[0];
    const float* w_ih0 = (const float*)d_in[1];
    const float* w_hh0 = (const float*)d_in[2];
    const float* b_ih0 = (const float*)d_in[3];
    const float* b_hh0 = (const float*)d_in[4];
    const float* w_ih1 = (const float*)d_in[5];
    const float* w_hh1 = (const float*)d_in[6];
    const float* b_ih1 = (const float*)d_in[7];
    const float* b_hh1 = (const float*)d_in[8];
    const float* fc1_w = (const float*)d_in[9];
    const float* fc1_b = (const float*)d_in[10];
    const float* fc2_w = (const float*)d_in[11];
    const float* fc2_b = (const float*)d_in[12];
    const float* fc3_w = (const float*)d_in[13];
    const float* fc3_b = (const float*)d_in[14];
    float* out = (float*)d_out;

    // ws layout: h buffer (98.304 MB) | y (0.768 MB) | z (0.768 MB)
    float* h_buf = (float*)d_ws;
    float* y_t   = (float*)((char*)d_ws + 98304000);
    float* z_t   = (float*)((char*)d_ws + 98304000 + 768000);

    lstm_layer0<<<dim3(BATCH), dim3(512), 0, stream>>>(x, w_ih0, w_hh0, b_ih0, b_hh0, h_buf);
    lstm_layer1<<<dim3(BATCH), dim3(512), 0, stream>>>(w_ih1, w_hh1, b_ih1, b_hh1, h_buf);

    const int nelem = T_STEPS * BATCH;
    fc_head<<<dim3((nelem + 255) / 256), dim3(256), 0, stream>>>(
        h_buf, fc1_w, fc1_b, fc2_w, fc2_b, fc3_w, fc3_b, y_t);
    deriv_k<<<dim3((nelem + 255) / 256), dim3(256), 0, stream>>>(y_t, z_t, 0);
    deriv_k<<<dim3((nelem + 255) / 256), dim3(256), 0, stream>>>(z_t, out, 1);
}

// Round 3
// 18577.837 us; speedup vs baseline: 1.9631x; 1.9631x over previous
//
#include <hip/hip_runtime.h>
#include <math.h>

// ---------------------------------------------------------------------------
// PhyRNN: 2-layer LSTM (B=64, T=3000, I=8, H=128) + FC head + double FD deriv.
//
// R3. History:
//  R1 16.6 ms: 512 thr/block, w[128]/thread -> VGPR capped at 128 -> spilled.
//  R2 36.5 ms: waves_per_eu(2,2) IGNORED (VGPR still 128); FETCH_SIZE 5.9 GB
//              = scratch refill storm. Lesson: don't need >128 VGPRs/thread.
//  R3: 1024 thr/block, each thread owns HALF a gate row (K=64 -> w[64] regs).
//      tid = j*8 + gt*2 + half. Half-combine via shfl_xor(1), gate combine
//      via shfl_xor(2/4). __launch_bounds__(1024,4) -> 128-VGPR cap, ~105
//      needed -> no spill. One barrier per step. Layer1: h1 chunk staged to
//      LDS coalesced; phase A (input proj) reads LDS; xp parked in LDS.
//
// Precision: fp32 (no fp32 MFMA on CDNA4; double FD derivative amplifies
// noise x2500, bf16 too risky).
// FMA floor: 65536 FMA/step/block / 128 lanes/CU = 512 cyc = 213 ns/step.
// ws: h buffer 98.304 MB + y 0.768 MB + z 0.768 MB.
// ---------------------------------------------------------------------------

#define T_STEPS 3000
#define BATCH   64
#define HID     128
#define CHUNK   24      // 3000 = 125 * 24; xp LDS = 24*512*4 = 48 KB
#define INV_DT  50.0f   // 1/0.02

__device__ __forceinline__ float sigmoid_(float x) {
    return 1.0f / (1.0f + __expf(-x));
}
__device__ __forceinline__ float tanh_(float x) {
    return 1.0f - 2.0f / (__expf(2.0f * x) + 1.0f);
}

// ---------------------------------------------------------------- layer 0 ---
// 64 blocks (1/batch), 1024 threads: j = tid>>3 (unit), gt = (tid>>1)&3,
// hf = tid&1 (K-half). Weight row r = gt*128+j, K-range [hf*64, hf*64+64).
__global__ __launch_bounds__(1024, 4)
void lstm_layer0(const float* __restrict__ x,      // [64][3000][8]
                 const float* __restrict__ w_ih,   // [512][8]
                 const float* __restrict__ w_hh,   // [512][128]
                 const float* __restrict__ b_ih,
                 const float* __restrict__ b_hh,
                 float* __restrict__ h_out)        // [64][3000][128]
{
    const int b   = blockIdx.x;
    const int tid = threadIdx.x;
    const int j   = tid >> 3;
    const int sub = tid & 7;
    const int gt  = sub >> 1;           // 0=i 1=f 2=g 3=o
    const int hf  = sub & 1;
    const int r   = gt * HID + j;
    const int kb  = hf * 64;

    __shared__ __align__(16) float h_s[2][HID];

    float w[64];                        // half of the W_hh row
#pragma unroll
    for (int i = 0; i < 64; i += 4) {
        float4 v = *(const float4*)(w_hh + (size_t)r * HID + kb + i);
        w[i] = v.x; w[i+1] = v.y; w[i+2] = v.z; w[i+3] = v.w;
    }
    float wi[8];
#pragma unroll
    for (int i = 0; i < 8; i += 4) {
        float4 v = *(const float4*)(w_ih + (size_t)r * 8 + i);
        wi[i] = v.x; wi[i+1] = v.y; wi[i+2] = v.z; wi[i+3] = v.w;
    }
    const float bias = b_ih[r] + b_hh[r];
    float c = 0.0f;                     // valid in sub==0 threads

    if (tid < HID) h_s[0][tid] = 0.0f;
    __syncthreads();

    const float* xrow = x + (size_t)b * T_STEPS * 8;
    float* hb = h_out + (size_t)b * T_STEPS * HID;

#pragma unroll 1
    for (int t = 0; t < T_STEPS; ++t) {
        const int rb = t & 1;
        float4 xa = *(const float4*)(xrow + t * 8);
        float4 xc = *(const float4*)(xrow + t * 8 + 4);
        float xterm = bias
                    + wi[0]*xa.x + wi[1]*xa.y + wi[2]*xa.z + wi[3]*xa.w
                    + wi[4]*xc.x + wi[5]*xc.y + wi[6]*xc.z + wi[7]*xc.w;
        float acc0 = hf ? 0.0f : xterm;      // x-term + bias added once
        float acc1 = 0.0f, acc2 = 0.0f, acc3 = 0.0f;
#pragma unroll
        for (int k4 = 0; k4 < 16; k4 += 4) {
            float4 h0 = *(const float4*)(&h_s[rb][kb + 4*k4]);
            float4 h1 = *(const float4*)(&h_s[rb][kb + 4*k4 + 4]);
            float4 h2 = *(const float4*)(&h_s[rb][kb + 4*k4 + 8]);
            float4 h3 = *(const float4*)(&h_s[rb][kb + 4*k4 + 12]);
            acc0 += w[4*k4   ]*h0.x + w[4*k4+ 1]*h0.y + w[4*k4+ 2]*h0.z + w[4*k4+ 3]*h0.w;
            acc1 += w[4*k4+ 4]*h1.x + w[4*k4+ 5]*h1.y + w[4*k4+ 6]*h1.z + w[4*k4+ 7]*h1.w;
            acc2 += w[4*k4+ 8]*h2.x + w[4*k4+ 9]*h2.y + w[4*k4+10]*h2.z + w[4*k4+11]*h2.w;
            acc3 += w[4*k4+12]*h3.x + w[4*k4+13]*h3.y + w[4*k4+14]*h3.z + w[4*k4+15]*h3.w;
        }
        float accs = (acc0 + acc1) + (acc2 + acc3);
        accs += __shfl_xor(accs, 1);         // combine K-halves

        float av = (gt == 2) ? tanh_(accs) : sigmoid_(accs);
        float t1 = __shfl_xor(av, 2);
        float t2 = __shfl_xor(av, 4);
        float t3 = __shfl_xor(t1, 4);
        if (sub == 0) {                      // av=sig(i) t1=sig(f) t2=tanh(g) t3=sig(o)
            c = t1 * c + av * t2;
            float h = t3 * tanh_(c);
            h_s[rb ^ 1][j] = h;
            hb[(size_t)t * HID + j] = h;
        }
        __syncthreads();
    }
}

// ---------------------------------------------------------------- layer 1 ---
// Per CHUNK: stage h1 chunk to LDS (coalesced), phase A computes
// xp[tau][j*4+gt] = bias + W_ih . h1 (parallel), phase B serial recurrence.
// h2 overwrites h1 in place (barriers order reads before writes).
__global__ __launch_bounds__(1024, 4)
void lstm_layer1(const float* __restrict__ w_ih,   // [512][128]
                 const float* __restrict__ w_hh,   // [512][128]
                 const float* __restrict__ b_ih,
                 const float* __restrict__ b_hh,
                 float* __restrict__ h_buf)        // in: h1, out: h2 (in place)
{
    const int b   = blockIdx.x;
    const int tid = threadIdx.x;
    const int j   = tid >> 3;
    const int sub = tid & 7;
    const int gt  = sub >> 1;
    const int hf  = sub & 1;
    const int r   = gt * HID + j;
    const int kb  = hf * 64;

    __shared__ __align__(16) float xp_s[CHUNK][512];       // 48 KB
    __shared__ __align__(16) float hch[CHUNK * HID];       // 12 KB
    __shared__ __align__(16) float h_s[2][HID];

    const float bias = b_ih[r] + b_hh[r];
    float c = 0.0f;
    if (tid < HID) h_s[0][tid] = 0.0f;
    __syncthreads();

    float* hbB = h_buf + (size_t)b * T_STEPS * HID;
    float w[64];

    for (int t0 = 0; t0 < T_STEPS; t0 += CHUNK) {
        // ---- stage h1 chunk -> LDS, coalesced (3072 floats = 768 float4)
        if (tid < 768) {
            ((float4*)hch)[tid] = ((const float4*)(hbB + (size_t)t0 * HID))[tid];
        }
        // ---- load W_ih half-row (L2-resident)
#pragma unroll
        for (int i = 0; i < 64; i += 4) {
            float4 v = *(const float4*)(w_ih + (size_t)r * HID + kb + i);
            w[i] = v.x; w[i+1] = v.y; w[i+2] = v.z; w[i+3] = v.w;
        }
        __syncthreads();   // hch visible; prev chunk's xp reads all complete

        // ---- phase A: xp_s[tau][j*4+gt] = bias + W_ih[r] . h1[t0+tau]
#pragma unroll 1
        for (int tau = 0; tau < CHUNK; ++tau) {
            const float* hr = hch + tau * HID + kb;
            float a0 = 0.0f, a1 = 0.0f, a2 = 0.0f, a3 = 0.0f;
#pragma unroll
            for (int k4 = 0; k4 < 16; k4 += 4) {
                float4 h0 = *(const float4*)(hr + 4*k4);
                float4 h1 = *(const float4*)(hr + 4*k4 + 4);
                float4 h2 = *(const float4*)(hr + 4*k4 + 8);
                float4 h3 = *(const float4*)(hr + 4*k4 + 12);
                a0 += w[4*k4   ]*h0.x + w[4*k4+ 1]*h0.y + w[4*k4+ 2]*h0.z + w[4*k4+ 3]*h0.w;
                a1 += w[4*k4+ 4]*h1.x + w[4*k4+ 5]*h1.y + w[4*k4+ 6]*h1.z + w[4*k4+ 7]*h1.w;
                a2 += w[4*k4+ 8]*h2.x + w[4*k4+ 9]*h2.y + w[4*k4+10]*h2.z + w[4*k4+11]*h2.w;
                a3 += w[4*k4+12]*h3.x + w[4*k4+13]*h3.y + w[4*k4+14]*h3.z + w[4*k4+15]*h3.w;
            }
            float a = (a0 + a1) + (a2 + a3);
            a += __shfl_xor(a, 1);
            if (hf == 0) xp_s[tau][tid >> 1] = bias + a;   // [24][512], conflict-free
        }
        // ---- swap to W_hh half-row
#pragma unroll
        for (int i = 0; i < 64; i += 4) {
            float4 v = *(const float4*)(w_hh + (size_t)r * HID + kb + i);
            w[i] = v.x; w[i+1] = v.y; w[i+2] = v.z; w[i+3] = v.w;
        }
        __syncthreads();   // xp_s visible; hch reads done

        // ---- phase B: serial recurrence
#pragma unroll 1
        for (int tt = 0; tt < CHUNK; ++tt) {
            const int t  = t0 + tt;
            const int rb = t & 1;
            float acc0 = hf ? 0.0f : xp_s[tt][tid >> 1];
            float acc1 = 0.0f, acc2 = 0.0f, acc3 = 0.0f;
#pragma unroll
            for (int k4 = 0; k4 < 16; k4 += 4) {
                float4 h0 = *(const float4*)(&h_s[rb][kb + 4*k4]);
                float4 h1 = *(const float4*)(&h_s[rb][kb + 4*k4 + 4]);
                float4 h2 = *(const float4*)(&h_s[rb][kb + 4*k4 + 8]);
                float4 h3 = *(const float4*)(&h_s[rb][kb + 4*k4 + 12]);
                acc0 += w[4*k4   ]*h0.x + w[4*k4+ 1]*h0.y + w[4*k4+ 2]*h0.z + w[4*k4+ 3]*h0.w;
                acc1 += w[4*k4+ 4]*h1.x + w[4*k4+ 5]*h1.y + w[4*k4+ 6]*h1.z + w[4*k4+ 7]*h1.w;
                acc2 += w[4*k4+ 8]*h2.x + w[4*k4+ 9]*h2.y + w[4*k4+10]*h2.z + w[4*k4+11]*h2.w;
                acc3 += w[4*k4+12]*h3.x + w[4*k4+13]*h3.y + w[4*k4+14]*h3.z + w[4*k4+15]*h3.w;
            }
            float accs = (acc0 + acc1) + (acc2 + acc3);
            accs += __shfl_xor(accs, 1);

            float av = (gt == 2) ? tanh_(accs) : sigmoid_(accs);
            float t1 = __shfl_xor(av, 2);
            float t2 = __shfl_xor(av, 4);
            float t3 = __shfl_xor(t1, 4);
            if (sub == 0) {
                c = t1 * c + av * t2;
                float h = t3 * tanh_(c);
                h_s[rb ^ 1][j] = h;
                hbB[(size_t)t * HID + j] = h;    // h2 overwrites h1
            }
            __syncthreads();
        }
    }
}

// ---------------------------------------------------------------- FC head ---
// b-major: idx = b*3000 + t. fc1 weights staged in LDS; 16 accumulators while
// streaming h once (no hv[128] per-thread array -> no spill).
__global__ __launch_bounds__(256)
void fc_head(const float* __restrict__ h_buf,  // h2 [64][3000][128]
             const float* __restrict__ fc1_w, const float* __restrict__ fc1_b,
             const float* __restrict__ fc2_w, const float* __restrict__ fc2_b,
             const float* __restrict__ fc3_w, const float* __restrict__ fc3_b,
             float* __restrict__ y_bt)         // [64][3000]
{
    __shared__ __align__(16) float w1[16 * HID];   // 8 KB
    __shared__ float sb[89];  // fc1_b[0:16) fc2_w[16:80) fc2_b[80:84) fc3_w[84:88) fc3_b[88]
    const int tid = threadIdx.x;
    for (int i = tid; i < 16 * HID; i += 256) w1[i] = fc1_w[i];
    if (tid < 16) sb[tid]      = fc1_b[tid];
    if (tid < 64) sb[16 + tid] = fc2_w[tid];
    if (tid < 4)  sb[80 + tid] = fc2_b[tid];
    if (tid < 4)  sb[84 + tid] = fc3_w[tid];
    if (tid == 0) sb[88]       = fc3_b[0];
    __syncthreads();

    const int idx = blockIdx.x * 256 + tid;        // b*3000 + t
    if (idx >= BATCH * T_STEPS) return;
    const float* h = h_buf + (size_t)idx * HID;

    float y1[16];
#pragma unroll
    for (int jo = 0; jo < 16; ++jo) y1[jo] = sb[jo];
#pragma unroll 4
    for (int k4 = 0; k4 < 32; ++k4) {
        float4 hv = *(const float4*)(h + 4 * k4);
#pragma unroll
        for (int jo = 0; jo < 16; ++jo) {
            float4 wv = *(const float4*)(&w1[jo * HID + 4 * k4]);
            y1[jo] += wv.x*hv.x + wv.y*hv.y + wv.z*hv.z + wv.w*hv.w;
        }
    }
    float y2[4];
#pragma unroll
    for (int jo = 0; jo < 4; ++jo) {
        float a = sb[80 + jo];
#pragma unroll
        for (int k = 0; k < 16; ++k) a += sb[16 + jo * 16 + k] * fmaxf(y1[k], 0.0f);
        y2[jo] = fmaxf(a, 0.0f);
    }
    float y = sb[88];
#pragma unroll
    for (int k = 0; k < 4; ++k) y += sb[84 + k] * y2[k];

    y_bt[idx] = y;   // coalesced (t fast)
}

// ------------------------------------------------------------- FD stencil ---
// b-major [64][3000]: neighbors are idx+-1 within a row; 2nd-order one-sided
// ends. Applied twice (phi @ (phi @ y)) -- exact, incl. boundary rows.
__global__ void deriv_k(const float* __restrict__ in,   // [64][3000]
                        float* __restrict__ outp)       // [64][3000]
{
    const int idx = blockIdx.x * blockDim.x + threadIdx.x;
    if (idx >= BATCH * T_STEPS) return;
    const int t = idx % T_STEPS;
    float v;
    if (t == 0) {
        v = (-1.5f * in[idx] + 2.0f * in[idx + 1] - 0.5f * in[idx + 2]) * INV_DT;
    } else if (t == T_STEPS - 1) {
        v = (0.5f * in[idx - 2] - 2.0f * in[idx - 1] + 1.5f * in[idx]) * INV_DT;
    } else {
        v = (in[idx + 1] - in[idx - 1]) * (0.5f * INV_DT);
    }
    outp[idx] = v;
}

// ------------------------------------------------------------------ launch --
extern "C" void kernel_launch(void* const* d_in, const int* in_sizes, int n_in,
                              void* d_out, int out_size, void* d_ws, size_t ws_size,
                              hipStream_t stream)
{
    const float* x     = (const float*)d_in[0];
    const float* w_ih0 = (const float*)d_in[1];
    const float* w_hh0 = (const float*)d_in[2];
    const float* b_ih0 = (const float*)d_in[3];
    const float* b_hh0 = (const float*)d_in[4];
    const float* w_ih1 = (const float*)d_in[5];
    const float* w_hh1 = (const float*)d_in[6];
    const float* b_ih1 = (const float*)d_in[7];
    const float* b_hh1 = (const float*)d_in[8];
    const float* fc1_w = (const float*)d_in[9];
    const float* fc1_b = (const float*)d_in[10];
    const float* fc2_w = (const float*)d_in[11];
    const float* fc2_b = (const float*)d_in[12];
    const float* fc3_w = (const float*)d_in[13];
    const float* fc3_b = (const float*)d_in[14];
    float* out = (float*)d_out;

    // ws layout: h buffer (98.304 MB) | y (0.768 MB) | z (0.768 MB)
    float* h_buf = (float*)d_ws;
    float* y_bt  = (float*)((char*)d_ws + 98304000);
    float* z_bt  = (float*)((char*)d_ws + 98304000 + 768000);

    lstm_layer0<<<dim3(BATCH), dim3(1024), 0, stream>>>(x, w_ih0, w_hh0, b_ih0, b_hh0, h_buf);
    lstm_layer1<<<dim3(BATCH), dim3(1024), 0, stream>>>(w_ih1, w_hh1, b_ih1, b_hh1, h_buf);

    const int nelem = T_STEPS * BATCH;   // 192000 = 750 * 256
    fc_head<<<dim3(nelem / 256), dim3(256), 0, stream>>>(
        h_buf, fc1_w, fc1_b, fc2_w, fc2_b, fc3_w, fc3_b, y_bt);
    deriv_k<<<dim3(nelem / 256), dim3(256), 0, stream>>>(y_bt, z_bt);
    deriv_k<<<dim3(nelem / 256), dim3(256), 0, stream>>>(z_bt, out);
}